// Round 7
// baseline (494.935 us; speedup 1.0000x reference)
//
#include <hip/hip_runtime.h>
#include <hip/hip_bf16.h>
#include <math.h>

typedef __bf16 bf16_t;
typedef __bf16 bf16x8 __attribute__((ext_vector_type(8)));
typedef __bf16 bf16x4 __attribute__((ext_vector_type(4)));
typedef float  f32x4  __attribute__((ext_vector_type(4)));

#define MFMA_BF16(a, b, c) __builtin_amdgcn_mfma_f32_16x16x32_bf16(a, b, c, 0, 0, 0)

#if __has_builtin(__builtin_amdgcn_exp2f)
__device__ __forceinline__ float fast_exp2(float x) { return __builtin_amdgcn_exp2f(x); }
#else
__device__ __forceinline__ float fast_exp2(float x) { return exp2f(x); }
#endif

// async global->LDS, 16B per lane; LDS dest is wave-uniform base + lane*16
__device__ __forceinline__ void gload_lds16(const bf16_t* g, bf16_t* l) {
  __builtin_amdgcn_global_load_lds(
      (const __attribute__((address_space(1))) void*)g,
      (__attribute__((address_space(3))) void*)l, 16, 0, 0);
}

// ---------------------------------------------------------------------------
// Transpose + fp32 -> bf16 convert:  in[K][N] fp32  ->  out[N][K] bf16
// ---------------------------------------------------------------------------
__global__ __launch_bounds__(256) void sa_transpose(const float* __restrict__ in,
                                                    bf16_t* __restrict__ out,
                                                    int K, int N) {
  __shared__ bf16_t tile[64][65];
  const int n0 = blockIdx.x * 64, k0 = blockIdx.y * 64;
  const int t = threadIdx.x;
#pragma unroll
  for (int i = 0; i < 16; ++i) {
    int idx = t + i * 256;
    int r = idx >> 6, c = idx & 63;
    tile[r][c] = (bf16_t)in[(size_t)(k0 + r) * N + n0 + c];
  }
  __syncthreads();
#pragma unroll
  for (int i = 0; i < 16; ++i) {
    int idx = t + i * 256;
    int r = idx >> 6, c = idx & 63;
    out[(size_t)(n0 + r) * K + k0 + c] = tile[c][r];
  }
}

// ---------------------------------------------------------------------------
// LayerNorm over D=1024, one block per row. Writes bf16 (always) + fp32 (opt).
// ---------------------------------------------------------------------------
__global__ __launch_bounds__(256) void sa_layernorm(const float* __restrict__ in,
                                                    const float* __restrict__ gamma,
                                                    const float* __restrict__ beta,
                                                    bf16_t* __restrict__ out_bf,
                                                    float* __restrict__ out_f) {
  const int row = blockIdx.x, t = threadIdx.x;
  const float4 v = *(const float4*)(in + (size_t)row * 1024 + t * 4);
  float s  = v.x + v.y + v.z + v.w;
  float ss = v.x * v.x + v.y * v.y + v.z * v.z + v.w * v.w;
#pragma unroll
  for (int m = 1; m < 64; m <<= 1) {
    s  += __shfl_xor(s, m, 64);
    ss += __shfl_xor(ss, m, 64);
  }
  __shared__ float red[8];
  const int w = t >> 6, lane = t & 63;
  if (lane == 0) { red[w] = s; red[4 + w] = ss; }
  __syncthreads();
  s  = red[0] + red[1] + red[2] + red[3];
  ss = red[4] + red[5] + red[6] + red[7];
  const float mu   = s * (1.f / 1024.f);
  const float rstd = rsqrtf(ss * (1.f / 1024.f) - mu * mu + 1e-5f);
  const float4 gv = *(const float4*)(gamma + t * 4);
  const float4 bv = *(const float4*)(beta + t * 4);
  const float y0 = (v.x - mu) * rstd * gv.x + bv.x;
  const float y1 = (v.y - mu) * rstd * gv.y + bv.y;
  const float y2 = (v.z - mu) * rstd * gv.z + bv.z;
  const float y3 = (v.w - mu) * rstd * gv.w + bv.w;
  bf16x4 ob = { (bf16_t)y0, (bf16_t)y1, (bf16_t)y2, (bf16_t)y3 };
  *(bf16x4*)(out_bf + (size_t)row * 1024 + t * 4) = ob;
  if (out_f) {
    float4 of = { y0, y1, y2, y3 };
    *(float4*)(out_f + (size_t)row * 1024 + t * 4) = of;
  }
}

// ---------------------------------------------------------------------------
// GEMM: C[M,N] = A[M,K] @ Bt[N,K]^T + bias, bf16 in, fp32 acc. m97 structure
// (proven best at these shapes): 128x128 tile, BK=64, linear LDS [128][64],
// global_load_lds width=16, 4 waves (2x2), 4x4 16x16x32 frags per wave.
// + bijective XCD swizzle (all grids are multiples of 8 blocks).
// EPI: 0 = QKV split (Q scaled by 0.125*log2e; V transposed [bh][d][L]),
//      1 = fp32 store, 2 = GELU->bf16, 3 = fp32 store + residual add.
// ---------------------------------------------------------------------------
template <int EPI>
__global__ __launch_bounds__(256) void sa_gemm(const bf16_t* __restrict__ A,
                                               const bf16_t* __restrict__ Bt,
                                               const float* __restrict__ bias,
                                               int K, int N,
                                               float* __restrict__ fout,
                                               bf16_t* __restrict__ bfout,
                                               const float* __restrict__ res,
                                               bf16_t* __restrict__ qb,
                                               bf16_t* __restrict__ kb,
                                               bf16_t* __restrict__ vb) {
  __shared__ __attribute__((aligned(16))) bf16_t As[128][64];  // linear (gload_lds dest)
  __shared__ __attribute__((aligned(16))) bf16_t Bs[128][64];

  // bijective XCD swizzle: chunk the grid into 8 contiguous ranges
  const int nwg = gridDim.x * gridDim.y;
  const int flat = blockIdx.y * gridDim.x + blockIdx.x;
  const int wg = (flat & 7) * (nwg >> 3) + (flat >> 3);
  const int bx = wg % gridDim.x, by = wg / gridDim.x;

  const int m0 = by * 128, n0 = bx * 128;
  const int t = threadIdx.x;
  const int w = t >> 6, lane = t & 63;
  const int wr = w >> 1, wc = w & 1;
  const int fr = lane & 15;
  const int fq = lane >> 4;
  const int srow = lane >> 3;          // 0..7 row within a 1KB chunk
  const int scol = (lane & 7) * 8;     // element col within row

  const f32x4 fzero = { 0.f, 0.f, 0.f, 0.f };
  f32x4 acc[4][4];
#pragma unroll
  for (int mi = 0; mi < 4; ++mi)
#pragma unroll
    for (int ni = 0; ni < 4; ++ni) acc[mi][ni] = fzero;

  for (int k0 = 0; k0 < K; k0 += 64) {
    __syncthreads();                   // prior iter done reading LDS
#pragma unroll
    for (int i = 0; i < 4; ++i) {
      const int c = w * 4 + i;         // chunk 0..15 (8 rows each)
      const int row = c * 8 + srow;
      gload_lds16(A  + (size_t)(m0 + row) * K + k0 + scol, &As[c * 8][0]);
      gload_lds16(Bt + (size_t)(n0 + row) * K + k0 + scol, &Bs[c * 8][0]);
    }
    __syncthreads();                   // drains vmcnt: LDS tile ready
#pragma unroll
    for (int kk = 0; kk < 2; ++kk) {
      bf16x8 af[4], bfrag[4];
#pragma unroll
      for (int mi = 0; mi < 4; ++mi)
        af[mi] = *(const bf16x8*)&As[wr * 64 + mi * 16 + fr][kk * 32 + fq * 8];
#pragma unroll
      for (int ni = 0; ni < 4; ++ni)
        bfrag[ni] = *(const bf16x8*)&Bs[wc * 64 + ni * 16 + fr][kk * 32 + fq * 8];
#pragma unroll
      for (int mi = 0; mi < 4; ++mi)
#pragma unroll
        for (int ni = 0; ni < 4; ++ni)
          acc[mi][ni] = MFMA_BF16(af[mi], bfrag[ni], acc[mi][ni]);
    }
  }

#pragma unroll
  for (int ni = 0; ni < 4; ++ni) {
    const int n = n0 + wc * 64 + ni * 16 + fr;
    const float bn = bias[n];
#pragma unroll
    for (int mi = 0; mi < 4; ++mi) {
      const int mbase = m0 + wr * 64 + mi * 16 + fq * 4;
      float vv[4];
#pragma unroll
      for (int r = 0; r < 4; ++r) vv[r] = acc[mi][ni][r] + bn;
      if constexpr (EPI == 0) {
        const int which = n >> 10;
        const int hh = (n >> 6) & 15;
        const int d = n & 63;
        const int b = mbase >> 11, l = mbase & 2047;
        if (which == 0) {
#pragma unroll
          for (int r = 0; r < 4; ++r)
            qb[((size_t)(b * 16 + hh) * 2048 + l + r) * 64 + d] =
                (bf16_t)(vv[r] * (0.125f * 1.44269504088896340736f));
        } else if (which == 1) {
#pragma unroll
          for (int r = 0; r < 4; ++r)
            kb[((size_t)(b * 16 + hh) * 2048 + l + r) * 64 + d] = (bf16_t)vv[r];
        } else {
          bf16x4 pv = { (bf16_t)vv[0], (bf16_t)vv[1], (bf16_t)vv[2], (bf16_t)vv[3] };
          *(bf16x4*)(vb + ((size_t)(b * 16 + hh) * 64 + d) * 2048 + l) = pv;
        }
      } else if constexpr (EPI == 1) {
#pragma unroll
        for (int r = 0; r < 4; ++r) fout[(size_t)(mbase + r) * N + n] = vv[r];
      } else if constexpr (EPI == 2) {
#pragma unroll
        for (int r = 0; r < 4; ++r) {
          float g = 0.5f * vv[r] * (1.f + erff(vv[r] * 0.70710678118654752f));
          bfout[(size_t)(mbase + r) * N + n] = (bf16_t)g;
        }
      } else {
#pragma unroll
        for (int r = 0; r < 4; ++r)
          fout[(size_t)(mbase + r) * N + n] = vv[r] + res[(size_t)(mbase + r) * N + n];
      }
    }
  }
}

// ---------------------------------------------------------------------------
// Flash attention, swapped-QK^T + fixed-reference softmax. LDS: unpadded
// [*][64] rows with 16B-unit XOR swizzle (unit ^= row&7) on every write and
// read (the zero-conflict pattern verified in the GEMM). P written as bf16x4
// (b64) at swizzled units. XCD-swizzled grid: each XCD keeps ~5 heads' K/V
// L2-resident. Q/K in [bh][L][64] (Q pre-scaled by 0.125*log2e); V transposed
// [bh][64][L]. Q staged through Ks (aliased).
// ---------------------------------------------------------------------------
__global__ __launch_bounds__(256) void sa_attn(const bf16_t* __restrict__ qb,
                                               const bf16_t* __restrict__ kb,
                                               const bf16_t* __restrict__ vb,
                                               bf16_t* __restrict__ out) {
  __shared__ __attribute__((aligned(16))) bf16_t Ks[64][64];      // also Q staging
  __shared__ __attribute__((aligned(16))) bf16_t Vt[64][64];      // Vt[d][kv]
  __shared__ __attribute__((aligned(16))) bf16_t Ps[4][16][64];   // P[q][kv] per wave

  // XCD swizzle: logical (qblk,bh) from chunked wg -> same-bh blocks co-XCD
  const int nwg = gridDim.x * gridDim.y;            // 2048
  const int flat = blockIdx.y * gridDim.x + blockIdx.x;
  const int wg = (flat & 7) * (nwg >> 3) + (flat >> 3);
  const int qblk = wg & 31, bh = wg >> 5;

  const int t = threadIdx.x, w = t >> 6, lane = t & 63;
  const int fr = lane & 15, fq = lane >> 4;
  const int fx = fr & 7;                            // XOR key for fragment rows
  const size_t base = (size_t)bh * 2048 * 64;
  const f32x4 fzero = { 0.f, 0.f, 0.f, 0.f };

  const int row0 = t >> 3;                 // 0..31 (chunk 0); chunk 1 = +32
  const int u0 = t & 7;                    // 16B unit index
  const int sc = (u0 ^ (row0 & 7)) * 8;    // swizzled col (row&7 same for +32)
  const int gc = u0 * 8;                   // global col

  // stage Q through Ks (swizzled), freed before first K tile lands
  *(bf16x8*)&Ks[row0][sc] =
      *(const bf16x8*)(qb + base + (size_t)(qblk * 64 + row0) * 64 + gc);
  *(bf16x8*)&Ks[row0 + 32][sc] =
      *(const bf16x8*)(qb + base + (size_t)(qblk * 64 + row0 + 32) * 64 + gc);

  // prefetch KV tile 0 into registers (in flight during Q read)
  bf16x8 kreg0, kreg1, vreg0, vreg1;
  kreg0 = *(const bf16x8*)(kb + base + (size_t)row0 * 64 + gc);
  kreg1 = *(const bf16x8*)(kb + base + (size_t)(row0 + 32) * 64 + gc);
  vreg0 = *(const bf16x8*)(vb + base + (size_t)row0 * 2048 + gc);
  vreg1 = *(const bf16x8*)(vb + base + (size_t)(row0 + 32) * 2048 + gc);

  __syncthreads();
  bf16x8 qf[2];
  qf[0] = *(const bf16x8*)&Ks[w * 16 + fr][((0 * 4 + fq) ^ fx) * 8];
  qf[1] = *(const bf16x8*)&Ks[w * 16 + fr][((1 * 4 + fq) ^ fx) * 8];

  f32x4 o_acc[4];
#pragma unroll
  for (int dt = 0; dt < 4; ++dt) o_acc[dt] = fzero;
  f32x4 l4 = fzero;

  for (int kv0 = 0; kv0 < 2048; kv0 += 64) {
    __syncthreads();   // prior compute (and qf reads) done with LDS
    *(bf16x8*)&Ks[row0][sc] = kreg0;
    *(bf16x8*)&Ks[row0 + 32][sc] = kreg1;
    *(bf16x8*)&Vt[row0][sc] = vreg0;
    *(bf16x8*)&Vt[row0 + 32][sc] = vreg1;
    if (kv0 + 64 < 2048) {
      const int kvn = kv0 + 64;
      kreg0 = *(const bf16x8*)(kb + base + (size_t)(kvn + row0) * 64 + gc);
      kreg1 = *(const bf16x8*)(kb + base + (size_t)(kvn + row0 + 32) * 64 + gc);
      vreg0 = *(const bf16x8*)(vb + base + (size_t)row0 * 2048 + kvn + gc);
      vreg1 = *(const bf16x8*)(vb + base + (size_t)(row0 + 32) * 2048 + kvn + gc);
    }
    __syncthreads();

    // S^T: s[kvt][r] = S[q = w*16+fr][kv = kvt*16 + fq*4 + r]
    f32x4 s[4];
#pragma unroll
    for (int kvt = 0; kvt < 4; ++kvt) s[kvt] = fzero;
    __builtin_amdgcn_s_setprio(1);
#pragma unroll
    for (int kk = 0; kk < 2; ++kk) {
#pragma unroll
      for (int kvt = 0; kvt < 4; ++kvt) {
        bf16x8 kf = *(const bf16x8*)&Ks[kvt * 16 + fr][((kk * 4 + fq) ^ fx) * 8];
        s[kvt] = MFMA_BF16(kf, qf[kk], s[kvt]);   // swapped operands
      }
    }
    __builtin_amdgcn_s_setprio(0);

    // fixed-reference softmax: p = exp2(s), accumulate l, pack to bf16
#pragma unroll
    for (int kvt = 0; kvt < 4; ++kvt) {
#pragma unroll
      for (int r = 0; r < 4; ++r) s[kvt][r] = fast_exp2(s[kvt][r]);
      l4 += s[kvt];
      bf16x4 pr = { (bf16_t)s[kvt][0], (bf16_t)s[kvt][1],
                    (bf16_t)s[kvt][2], (bf16_t)s[kvt][3] };
      // logical col = kvt*16 + fq*4 -> unit kvt*2+(fq>>1), half (fq&1)
      *(bf16x4*)&Ps[w][fr][(((kvt * 2 + (fq >> 1)) ^ fx) * 8) + (fq & 1) * 4] = pr;
    }

    __builtin_amdgcn_s_setprio(1);
#pragma unroll
    for (int ks = 0; ks < 2; ++ks) {
      bf16x8 pf = *(const bf16x8*)&Ps[w][fr][((ks * 4 + fq) ^ fx) * 8];
#pragma unroll
      for (int dt = 0; dt < 4; ++dt) {
        bf16x8 vf = *(const bf16x8*)&Vt[dt * 16 + fr][((ks * 4 + fq) ^ fx) * 8];
        o_acc[dt] = MFMA_BF16(vf, pf, o_acc[dt]);
      }
    }
    __builtin_amdgcn_s_setprio(0);
  }

  float l_run = l4[0] + l4[1] + l4[2] + l4[3];
  l_run += __shfl_xor(l_run, 16, 64);
  l_run += __shfl_xor(l_run, 32, 64);
  const float linv = 1.f / l_run;
  const int b = bh >> 4, h = bh & 15;
  const int qg = qblk * 64 + w * 16 + fr;
#pragma unroll
  for (int dt = 0; dt < 4; ++dt) {
    bf16x4 ov;
#pragma unroll
    for (int r = 0; r < 4; ++r) ov[r] = (bf16_t)(o_acc[dt][r] * linv);
    const int d = dt * 16 + fq * 4;
    *(bf16x4*)(out + ((size_t)(b * 2048 + qg)) * 1024 + h * 64 + d) = ov;
  }
}

// ---------------------------------------------------------------------------
extern "C" void kernel_launch(void* const* d_in, const int* in_sizes, int n_in,
                              void* d_out, int out_size, void* d_ws, size_t ws_size,
                              hipStream_t stream) {
  const float* x      = (const float*)d_in[0];
  const float* qkv_w  = (const float*)d_in[1];
  const float* qkv_b  = (const float*)d_in[2];
  const float* out_w  = (const float*)d_in[3];
  const float* out_b  = (const float*)d_in[4];
  const float* ln1_g  = (const float*)d_in[5];
  const float* ln1_b  = (const float*)d_in[6];
  const float* ln2_g  = (const float*)d_in[7];
  const float* ln2_b  = (const float*)d_in[8];
  const float* ffn_w1 = (const float*)d_in[9];
  const float* ffn_b1 = (const float*)d_in[10];
  const float* ffn_w2 = (const float*)d_in[11];
  const float* ffn_b2 = (const float*)d_in[12];
  float* outp = (float*)d_out;

  char* p = (char*)d_ws;
  auto alloc = [&](size_t bytes) { char* r = p; p += bytes; return r; };
  bf16_t* qkvw_t = (bf16_t*)alloc((size_t)3072 * 1024 * 2);
  bf16_t* outw_t = (bf16_t*)alloc((size_t)1024 * 1024 * 2);
  bf16_t* w1_t   = (bf16_t*)alloc((size_t)4096 * 1024 * 2);
  bf16_t* w2_t   = (bf16_t*)alloc((size_t)1024 * 4096 * 2);
  bf16_t* h_bf   = (bf16_t*)alloc((size_t)8192 * 1024 * 2);
  bf16_t* q_buf  = (bf16_t*)alloc((size_t)8192 * 1024 * 2);
  bf16_t* k_buf  = (bf16_t*)alloc((size_t)8192 * 1024 * 2);
  bf16_t* v_buf  = (bf16_t*)alloc((size_t)8192 * 1024 * 2);
  bf16_t* a_bf   = (bf16_t*)alloc((size_t)8192 * 1024 * 2);
  float*  o_f    = (float*) alloc((size_t)8192 * 1024 * 4);
  float*  out_f  = (float*) alloc((size_t)8192 * 1024 * 4);
  bf16_t* out_bf = (bf16_t*)alloc((size_t)8192 * 1024 * 2);
  bf16_t* t_bf   = (bf16_t*)alloc((size_t)8192 * 4096 * 2);

  sa_transpose<<<dim3(3072 / 64, 1024 / 64), 256, 0, stream>>>(qkv_w, qkvw_t, 1024, 3072);
  sa_transpose<<<dim3(1024 / 64, 1024 / 64), 256, 0, stream>>>(out_w, outw_t, 1024, 1024);
  sa_transpose<<<dim3(4096 / 64, 1024 / 64), 256, 0, stream>>>(ffn_w1, w1_t, 1024, 4096);
  sa_transpose<<<dim3(1024 / 64, 4096 / 64), 256, 0, stream>>>(ffn_w2, w2_t, 4096, 1024);

  sa_layernorm<<<8192, 256, 0, stream>>>(x, ln1_g, ln1_b, h_bf, nullptr);

  sa_gemm<0><<<dim3(3072 / 128, 8192 / 128), 256, 0, stream>>>(
      h_bf, qkvw_t, qkv_b, 1024, 3072, nullptr, nullptr, nullptr, q_buf, k_buf, v_buf);

  sa_attn<<<dim3(32, 64), 256, 0, stream>>>(q_buf, k_buf, v_buf, a_bf);

  sa_gemm<1><<<dim3(1024 / 128, 8192 / 128), 256, 0, stream>>>(
      a_bf, outw_t, out_b, 1024, 1024, o_f, nullptr, nullptr, nullptr, nullptr, nullptr);

  sa_layernorm<<<8192, 256, 0, stream>>>(o_f, ln2_g, ln2_b, out_bf, out_f);

  sa_gemm<2><<<dim3(4096 / 128, 8192 / 128), 256, 0, stream>>>(
      out_bf, w1_t, ffn_b1, 1024, 4096, nullptr, t_bf, nullptr, nullptr, nullptr, nullptr);

  sa_gemm<3><<<dim3(1024 / 128, 8192 / 128), 256, 0, stream>>>(
      t_bf, w2_t, ffn_b2, 4096, 1024, outp, nullptr, out_f, nullptr, nullptr, nullptr);
}

// Round 8
// 456.404 us; speedup vs baseline: 1.0844x; 1.0844x over previous
//
#include <hip/hip_runtime.h>
#include <hip/hip_bf16.h>
#include <math.h>

typedef __bf16 bf16_t;
typedef __bf16 bf16x8 __attribute__((ext_vector_type(8)));
typedef __bf16 bf16x4 __attribute__((ext_vector_type(4)));
typedef float  f32x4  __attribute__((ext_vector_type(4)));

#define MFMA_BF16(a, b, c) __builtin_amdgcn_mfma_f32_16x16x32_bf16(a, b, c, 0, 0, 0)

#if __has_builtin(__builtin_amdgcn_exp2f)
__device__ __forceinline__ float fast_exp2(float x) { return __builtin_amdgcn_exp2f(x); }
#else
__device__ __forceinline__ float fast_exp2(float x) { return exp2f(x); }
#endif

// NaN-safe tanh-form GELU: g = v - v/(exp2(k*u)+1), u = v(1+0.044715 v^2),
// k = 2*0.7978845608*log2(e). Saturates correctly for |v| large.
__device__ __forceinline__ float fast_gelu(float v) {
  const float u = v * (1.f + 0.044715f * v * v);
  const float tt = fast_exp2(2.3022078f * u);
  return v - v / (tt + 1.f);
}

// async global->LDS, 16B per lane; LDS dest is wave-uniform base + lane*16
__device__ __forceinline__ void gload_lds16(const bf16_t* g, bf16_t* l) {
  __builtin_amdgcn_global_load_lds(
      (const __attribute__((address_space(1))) void*)g,
      (__attribute__((address_space(3))) void*)l, 16, 0, 0);
}

// ---------------------------------------------------------------------------
// Transpose + fp32 -> bf16 convert:  in[K][N] fp32  ->  out[N][K] bf16
// ---------------------------------------------------------------------------
__global__ __launch_bounds__(256) void sa_transpose(const float* __restrict__ in,
                                                    bf16_t* __restrict__ out,
                                                    int K, int N) {
  __shared__ bf16_t tile[64][65];
  const int n0 = blockIdx.x * 64, k0 = blockIdx.y * 64;
  const int t = threadIdx.x;
#pragma unroll
  for (int i = 0; i < 16; ++i) {
    int idx = t + i * 256;
    int r = idx >> 6, c = idx & 63;
    tile[r][c] = (bf16_t)in[(size_t)(k0 + r) * N + n0 + c];
  }
  __syncthreads();
#pragma unroll
  for (int i = 0; i < 16; ++i) {
    int idx = t + i * 256;
    int r = idx >> 6, c = idx & 63;
    out[(size_t)(n0 + r) * K + k0 + c] = tile[c][r];
  }
}

// ---------------------------------------------------------------------------
// LayerNorm over D=1024, one block per row. Writes bf16 (always) + fp32 (opt).
// ---------------------------------------------------------------------------
__global__ __launch_bounds__(256) void sa_layernorm(const float* __restrict__ in,
                                                    const float* __restrict__ gamma,
                                                    const float* __restrict__ beta,
                                                    bf16_t* __restrict__ out_bf,
                                                    float* __restrict__ out_f) {
  const int row = blockIdx.x, t = threadIdx.x;
  const float4 v = *(const float4*)(in + (size_t)row * 1024 + t * 4);
  float s  = v.x + v.y + v.z + v.w;
  float ss = v.x * v.x + v.y * v.y + v.z * v.z + v.w * v.w;
#pragma unroll
  for (int m = 1; m < 64; m <<= 1) {
    s  += __shfl_xor(s, m, 64);
    ss += __shfl_xor(ss, m, 64);
  }
  __shared__ float red[8];
  const int w = t >> 6, lane = t & 63;
  if (lane == 0) { red[w] = s; red[4 + w] = ss; }
  __syncthreads();
  s  = red[0] + red[1] + red[2] + red[3];
  ss = red[4] + red[5] + red[6] + red[7];
  const float mu   = s * (1.f / 1024.f);
  const float rstd = rsqrtf(ss * (1.f / 1024.f) - mu * mu + 1e-5f);
  const float4 gv = *(const float4*)(gamma + t * 4);
  const float4 bv = *(const float4*)(beta + t * 4);
  const float y0 = (v.x - mu) * rstd * gv.x + bv.x;
  const float y1 = (v.y - mu) * rstd * gv.y + bv.y;
  const float y2 = (v.z - mu) * rstd * gv.z + bv.z;
  const float y3 = (v.w - mu) * rstd * gv.w + bv.w;
  bf16x4 ob = { (bf16_t)y0, (bf16_t)y1, (bf16_t)y2, (bf16_t)y3 };
  *(bf16x4*)(out_bf + (size_t)row * 1024 + t * 4) = ob;
  if (out_f) {
    float4 of = { y0, y1, y2, y3 };
    *(float4*)(out_f + (size_t)row * 1024 + t * 4) = of;
  }
}

// ---------------------------------------------------------------------------
// Pipelined GEMM v3 (best measured GEMM at these shapes, r6):
// C[M,N] = A[M,K] @ Bt[N,K]^T + bias, bf16 in, fp32 acc.
// BM=256, BN=128, BK=64, 8 waves (4M x 2N, per-wave 64x64), 512 threads.
// 3 LDS buffers (144 KB), 2-K-tile prefetch lead. Per K-tile body:
//   [vmcnt(6)] [s_barrier] [issue 6 gload_lds for tile t+2 -> buf (t+2)%3]
//   [16 ds_read_b128 + 32 MFMA]
// LDS XOR-swizzle col16 ^= row&7 on both stage-source and ds_read (zero bank
// conflicts, r6 PMC). Bijective XCD swizzle (all grids are multiples of 8).
// EPI: 0 = QKV split (Q scaled by 0.125*log2e; V transposed [bh][d][L]),
//      1 = fp32 store, 2 = fast-GELU->bf16, 3 = fp32 store + residual add.
// ---------------------------------------------------------------------------
template <int EPI>
__global__ __launch_bounds__(512, 2) void sa_gemm3(const bf16_t* __restrict__ A,
                                                   const bf16_t* __restrict__ Bt,
                                                   const float* __restrict__ bias,
                                                   int K, int N,
                                                   float* __restrict__ fout,
                                                   bf16_t* __restrict__ bfout,
                                                   const float* __restrict__ res,
                                                   bf16_t* __restrict__ qb,
                                                   bf16_t* __restrict__ kb,
                                                   bf16_t* __restrict__ vb) {
  __shared__ __attribute__((aligned(16))) bf16_t As[3][256][64];  // 96 KB
  __shared__ __attribute__((aligned(16))) bf16_t Bs[3][128][64];  // 48 KB

  // bijective XCD swizzle (grid counts here are all multiples of 8)
  const int nwg = gridDim.x * gridDim.y;
  const int flat = blockIdx.y * gridDim.x + blockIdx.x;
  const int wg = (flat & 7) * (nwg >> 3) + (flat >> 3);
  const int bx = wg % gridDim.x, by = wg / gridDim.x;

  const int m0 = by * 256, n0 = bx * 128;
  const int t = threadIdx.x;
  const int wid = t >> 6, lane = t & 63;
  const int wm = wid >> 1, wn = wid & 1;        // 4M x 2N
  const int fr = lane & 15, fq = lane >> 4;
  const int swz = fr & 7;
  const int srow = lane >> 3;                   // 0..7 within an 8-row wave slice
  const int scol = ((lane & 7) ^ srow) * 8;     // pre-swizzled source col (elems)
  const int NT = K >> 6;

  const f32x4 fzero = { 0.f, 0.f, 0.f, 0.f };
  f32x4 acc[4][4];
#pragma unroll
  for (int mi = 0; mi < 4; ++mi)
#pragma unroll
    for (int ni = 0; ni < 4; ++ni) acc[mi][ni] = fzero;

  // stage full K-tile tt into buffer sb: A 32KB (4 issues) + B 16KB (2 issues)
  auto stage = [&](int tt, int sb) {
#pragma unroll
    for (int i = 0; i < 4; ++i)
      gload_lds16(A + (size_t)(m0 + i * 64 + wid * 8 + srow) * K + tt * 64 + scol,
                  &As[sb][i * 64 + wid * 8][0]);
#pragma unroll
    for (int i = 0; i < 2; ++i)
      gload_lds16(Bt + (size_t)(n0 + i * 64 + wid * 8 + srow) * K + tt * 64 + scol,
                  &Bs[sb][i * 64 + wid * 8][0]);
  };

  // prologue: tiles 0 and 1 in flight (12 loads)
  stage(0, 0);
  stage(1, 1);

  for (int tt = 0; tt < NT; ++tt) {
    const int c = tt % 3;
    if (tt + 1 < NT) asm volatile("s_waitcnt vmcnt(6)" ::: "memory");
    else             asm volatile("s_waitcnt vmcnt(0)" ::: "memory");
    __builtin_amdgcn_s_barrier();
    if (tt + 2 < NT) stage(tt + 2, (tt + 2) % 3);

    bf16x8 af[4][2], bfr[4][2];
#pragma unroll
    for (int mi = 0; mi < 4; ++mi)
#pragma unroll
      for (int kk = 0; kk < 2; ++kk)
        af[mi][kk] = *(const bf16x8*)&As[c][wm * 64 + mi * 16 + fr][((kk * 4 + fq) ^ swz) * 8];
#pragma unroll
    for (int ni = 0; ni < 4; ++ni)
#pragma unroll
      for (int kk = 0; kk < 2; ++kk)
        bfr[ni][kk] = *(const bf16x8*)&Bs[c][wn * 64 + ni * 16 + fr][((kk * 4 + fq) ^ swz) * 8];

    __builtin_amdgcn_s_setprio(1);
#pragma unroll
    for (int kk = 0; kk < 2; ++kk)
#pragma unroll
      for (int mi = 0; mi < 4; ++mi)
#pragma unroll
        for (int ni = 0; ni < 4; ++ni)
          acc[mi][ni] = MFMA_BF16(af[mi][kk], bfr[ni][kk], acc[mi][ni]);
    __builtin_amdgcn_s_setprio(0);
  }

#pragma unroll
  for (int ni = 0; ni < 4; ++ni) {
    const int n = n0 + wn * 64 + ni * 16 + fr;
    const float bn = bias[n];
#pragma unroll
    for (int mi = 0; mi < 4; ++mi) {
      const int mbase = m0 + wm * 64 + mi * 16 + fq * 4;
      float vv[4];
#pragma unroll
      for (int r = 0; r < 4; ++r) vv[r] = acc[mi][ni][r] + bn;
      if constexpr (EPI == 0) {
        const int which = n >> 10;
        const int hh = (n >> 6) & 15;
        const int d = n & 63;
        const int b = mbase >> 11, l = mbase & 2047;
        if (which == 0) {
#pragma unroll
          for (int r = 0; r < 4; ++r)
            qb[((size_t)(b * 16 + hh) * 2048 + l + r) * 64 + d] =
                (bf16_t)(vv[r] * (0.125f * 1.44269504088896340736f));
        } else if (which == 1) {
#pragma unroll
          for (int r = 0; r < 4; ++r)
            kb[((size_t)(b * 16 + hh) * 2048 + l + r) * 64 + d] = (bf16_t)vv[r];
        } else {
          bf16x4 pv = { (bf16_t)vv[0], (bf16_t)vv[1], (bf16_t)vv[2], (bf16_t)vv[3] };
          *(bf16x4*)(vb + ((size_t)(b * 16 + hh) * 64 + d) * 2048 + l) = pv;
        }
      } else if constexpr (EPI == 1) {
#pragma unroll
        for (int r = 0; r < 4; ++r) fout[(size_t)(mbase + r) * N + n] = vv[r];
      } else if constexpr (EPI == 2) {
#pragma unroll
        for (int r = 0; r < 4; ++r)
          bfout[(size_t)(mbase + r) * N + n] = (bf16_t)fast_gelu(vv[r]);
      } else {
#pragma unroll
        for (int r = 0; r < 4; ++r)
          fout[(size_t)(mbase + r) * N + n] = vv[r] + res[(size_t)(mbase + r) * N + n];
      }
    }
  }
}

// ---------------------------------------------------------------------------
// Flash attention, swapped-QK^T + fixed-reference softmax. LDS: unpadded
// [*][64] rows with 16B-unit XOR swizzle (unit ^= row&7) on every write and
// read. P written as bf16x4 (b64) at swizzled units. XCD-swizzled grid.
// Q/K in [bh][L][64] (Q pre-scaled by 0.125*log2e); V transposed [bh][64][L].
// Q staged through Ks (aliased).
// ---------------------------------------------------------------------------
__global__ __launch_bounds__(256) void sa_attn(const bf16_t* __restrict__ qb,
                                               const bf16_t* __restrict__ kb,
                                               const bf16_t* __restrict__ vb,
                                               bf16_t* __restrict__ out) {
  __shared__ __attribute__((aligned(16))) bf16_t Ks[64][64];      // also Q staging
  __shared__ __attribute__((aligned(16))) bf16_t Vt[64][64];      // Vt[d][kv]
  __shared__ __attribute__((aligned(16))) bf16_t Ps[4][16][64];   // P[q][kv] per wave

  // XCD swizzle: same-bh blocks co-XCD
  const int nwg = gridDim.x * gridDim.y;            // 2048
  const int flat = blockIdx.y * gridDim.x + blockIdx.x;
  const int wg = (flat & 7) * (nwg >> 3) + (flat >> 3);
  const int qblk = wg & 31, bh = wg >> 5;

  const int t = threadIdx.x, w = t >> 6, lane = t & 63;
  const int fr = lane & 15, fq = lane >> 4;
  const int fx = fr & 7;                            // XOR key for fragment rows
  const size_t base = (size_t)bh * 2048 * 64;
  const f32x4 fzero = { 0.f, 0.f, 0.f, 0.f };

  const int row0 = t >> 3;                 // 0..31 (chunk 0); chunk 1 = +32
  const int u0 = t & 7;                    // 16B unit index
  const int sc = (u0 ^ (row0 & 7)) * 8;    // swizzled col
  const int gc = u0 * 8;                   // global col

  // stage Q through Ks (swizzled), freed before first K tile lands
  *(bf16x8*)&Ks[row0][sc] =
      *(const bf16x8*)(qb + base + (size_t)(qblk * 64 + row0) * 64 + gc);
  *(bf16x8*)&Ks[row0 + 32][sc] =
      *(const bf16x8*)(qb + base + (size_t)(qblk * 64 + row0 + 32) * 64 + gc);

  // prefetch KV tile 0 into registers (in flight during Q read)
  bf16x8 kreg0, kreg1, vreg0, vreg1;
  kreg0 = *(const bf16x8*)(kb + base + (size_t)row0 * 64 + gc);
  kreg1 = *(const bf16x8*)(kb + base + (size_t)(row0 + 32) * 64 + gc);
  vreg0 = *(const bf16x8*)(vb + base + (size_t)row0 * 2048 + gc);
  vreg1 = *(const bf16x8*)(vb + base + (size_t)(row0 + 32) * 2048 + gc);

  __syncthreads();
  bf16x8 qf[2];
  qf[0] = *(const bf16x8*)&Ks[w * 16 + fr][((0 * 4 + fq) ^ fx) * 8];
  qf[1] = *(const bf16x8*)&Ks[w * 16 + fr][((1 * 4 + fq) ^ fx) * 8];

  f32x4 o_acc[4];
#pragma unroll
  for (int dt = 0; dt < 4; ++dt) o_acc[dt] = fzero;
  f32x4 l4 = fzero;

  for (int kv0 = 0; kv0 < 2048; kv0 += 64) {
    __syncthreads();
    *(bf16x8*)&Ks[row0][sc] = kreg0;
    *(bf16x8*)&Ks[row0 + 32][sc] = kreg1;
    *(bf16x8*)&Vt[row0][sc] = vreg0;
    *(bf16x8*)&Vt[row0 + 32][sc] = vreg1;
    if (kv0 + 64 < 2048) {
      const int kvn = kv0 + 64;
      kreg0 = *(const bf16x8*)(kb + base + (size_t)(kvn + row0) * 64 + gc);
      kreg1 = *(const bf16x8*)(kb + base + (size_t)(kvn + row0 + 32) * 64 + gc);
      vreg0 = *(const bf16x8*)(vb + base + (size_t)row0 * 2048 + kvn + gc);
      vreg1 = *(const bf16x8*)(vb + base + (size_t)(row0 + 32) * 2048 + kvn + gc);
    }
    __syncthreads();

    // S^T: s[kvt][r] = S[q = w*16+fr][kv = kvt*16 + fq*4 + r]
    f32x4 s[4];
#pragma unroll
    for (int kvt = 0; kvt < 4; ++kvt) s[kvt] = fzero;
    __builtin_amdgcn_s_setprio(1);
#pragma unroll
    for (int kk = 0; kk < 2; ++kk) {
#pragma unroll
      for (int kvt = 0; kvt < 4; ++kvt) {
        bf16x8 kf = *(const bf16x8*)&Ks[kvt * 16 + fr][((kk * 4 + fq) ^ fx) * 8];
        s[kvt] = MFMA_BF16(kf, qf[kk], s[kvt]);   // swapped operands
      }
    }
    __builtin_amdgcn_s_setprio(0);

    // fixed-reference softmax: p = exp2(s), accumulate l, pack to bf16
#pragma unroll
    for (int kvt = 0; kvt < 4; ++kvt) {
#pragma unroll
      for (int r = 0; r < 4; ++r) s[kvt][r] = fast_exp2(s[kvt][r]);
      l4 += s[kvt];
      bf16x4 pr = { (bf16_t)s[kvt][0], (bf16_t)s[kvt][1],
                    (bf16_t)s[kvt][2], (bf16_t)s[kvt][3] };
      *(bf16x4*)&Ps[w][fr][(((kvt * 2 + (fq >> 1)) ^ fx) * 8) + (fq & 1) * 4] = pr;
    }

    __builtin_amdgcn_s_setprio(1);
#pragma unroll
    for (int ks = 0; ks < 2; ++ks) {
      bf16x8 pf = *(const bf16x8*)&Ps[w][fr][((ks * 4 + fq) ^ fx) * 8];
#pragma unroll
      for (int dt = 0; dt < 4; ++dt) {
        bf16x8 vf = *(const bf16x8*)&Vt[dt * 16 + fr][((ks * 4 + fq) ^ fx) * 8];
        o_acc[dt] = MFMA_BF16(vf, pf, o_acc[dt]);
      }
    }
    __builtin_amdgcn_s_setprio(0);
  }

  float l_run = l4[0] + l4[1] + l4[2] + l4[3];
  l_run += __shfl_xor(l_run, 16, 64);
  l_run += __shfl_xor(l_run, 32, 64);
  const float linv = 1.f / l_run;
  const int b = bh >> 4, h = bh & 15;
  const int qg = qblk * 64 + w * 16 + fr;
#pragma unroll
  for (int dt = 0; dt < 4; ++dt) {
    bf16x4 ov;
#pragma unroll
    for (int r = 0; r < 4; ++r) ov[r] = (bf16_t)(o_acc[dt][r] * linv);
    const int d = dt * 16 + fq * 4;
    *(bf16x4*)(out + ((size_t)(b * 2048 + qg)) * 1024 + h * 64 + d) = ov;
  }
}

// ---------------------------------------------------------------------------
extern "C" void kernel_launch(void* const* d_in, const int* in_sizes, int n_in,
                              void* d_out, int out_size, void* d_ws, size_t ws_size,
                              hipStream_t stream) {
  const float* x      = (const float*)d_in[0];
  const float* qkv_w  = (const float*)d_in[1];
  const float* qkv_b  = (const float*)d_in[2];
  const float* out_w  = (const float*)d_in[3];
  const float* out_b  = (const float*)d_in[4];
  const float* ln1_g  = (const float*)d_in[5];
  const float* ln1_b  = (const float*)d_in[6];
  const float* ln2_g  = (const float*)d_in[7];
  const float* ln2_b  = (const float*)d_in[8];
  const float* ffn_w1 = (const float*)d_in[9];
  const float* ffn_b1 = (const float*)d_in[10];
  const float* ffn_w2 = (const float*)d_in[11];
  const float* ffn_b2 = (const float*)d_in[12];
  float* outp = (float*)d_out;

  char* p = (char*)d_ws;
  auto alloc = [&](size_t bytes) { char* r = p; p += bytes; return r; };
  bf16_t* qkvw_t = (bf16_t*)alloc((size_t)3072 * 1024 * 2);
  bf16_t* outw_t = (bf16_t*)alloc((size_t)1024 * 1024 * 2);
  bf16_t* w1_t   = (bf16_t*)alloc((size_t)4096 * 1024 * 2);
  bf16_t* w2_t   = (bf16_t*)alloc((size_t)1024 * 4096 * 2);
  bf16_t* h_bf   = (bf16_t*)alloc((size_t)8192 * 1024 * 2);
  bf16_t* q_buf  = (bf16_t*)alloc((size_t)8192 * 1024 * 2);
  bf16_t* k_buf  = (bf16_t*)alloc((size_t)8192 * 1024 * 2);
  bf16_t* v_buf  = (bf16_t*)alloc((size_t)8192 * 1024 * 2);
  bf16_t* a_bf   = (bf16_t*)alloc((size_t)8192 * 1024 * 2);
  float*  o_f    = (float*) alloc((size_t)8192 * 1024 * 4);
  float*  out_f  = (float*) alloc((size_t)8192 * 1024 * 4);
  bf16_t* out_bf = (bf16_t*)alloc((size_t)8192 * 1024 * 2);
  bf16_t* t_bf   = (bf16_t*)alloc((size_t)8192 * 4096 * 2);

  sa_transpose<<<dim3(3072 / 64, 1024 / 64), 256, 0, stream>>>(qkv_w, qkvw_t, 1024, 3072);
  sa_transpose<<<dim3(1024 / 64, 1024 / 64), 256, 0, stream>>>(out_w, outw_t, 1024, 1024);
  sa_transpose<<<dim3(4096 / 64, 1024 / 64), 256, 0, stream>>>(ffn_w1, w1_t, 1024, 4096);
  sa_transpose<<<dim3(1024 / 64, 4096 / 64), 256, 0, stream>>>(ffn_w2, w2_t, 4096, 1024);

  sa_layernorm<<<8192, 256, 0, stream>>>(x, ln1_g, ln1_b, h_bf, nullptr);

  sa_gemm3<0><<<dim3(3072 / 128, 8192 / 256), 512, 0, stream>>>(
      h_bf, qkvw_t, qkv_b, 1024, 3072, nullptr, nullptr, nullptr, q_buf, k_buf, v_buf);

  sa_attn<<<dim3(32, 64), 256, 0, stream>>>(q_buf, k_buf, v_buf, a_bf);

  sa_gemm3<1><<<dim3(1024 / 128, 8192 / 256), 512, 0, stream>>>(
      a_bf, outw_t, out_b, 1024, 1024, o_f, nullptr, nullptr, nullptr, nullptr, nullptr);

  sa_layernorm<<<8192, 256, 0, stream>>>(o_f, ln2_g, ln2_b, out_bf, out_f);

  sa_gemm3<2><<<dim3(4096 / 128, 8192 / 256), 512, 0, stream>>>(
      out_bf, w1_t, ffn_b1, 1024, 4096, nullptr, t_bf, nullptr, nullptr, nullptr, nullptr);

  sa_gemm3<3><<<dim3(1024 / 128, 8192 / 256), 512, 0, stream>>>(
      t_bf, w2_t, ffn_b2, 4096, 1024, outp, nullptr, out_f, nullptr, nullptr, nullptr);
}

// Round 9
// 395.247 us; speedup vs baseline: 1.2522x; 1.1547x over previous
//
#include <hip/hip_runtime.h>
#include <hip/hip_bf16.h>
#include <math.h>

typedef __bf16 bf16_t;
typedef __bf16 bf16x8 __attribute__((ext_vector_type(8)));
typedef __bf16 bf16x4 __attribute__((ext_vector_type(4)));
typedef float  f32x4  __attribute__((ext_vector_type(4)));

#define MFMA_BF16(a, b, c) __builtin_amdgcn_mfma_f32_16x16x32_bf16(a, b, c, 0, 0, 0)

#if __has_builtin(__builtin_amdgcn_exp2f)
__device__ __forceinline__ float fast_exp2(float x) { return __builtin_amdgcn_exp2f(x); }
#else
__device__ __forceinline__ float fast_exp2(float x) { return exp2f(x); }
#endif

// NaN-safe tanh-form GELU: g = v - v/(exp2(k*u)+1), u = v(1+0.044715 v^2).
__device__ __forceinline__ float fast_gelu(float v) {
  const float u = v * (1.f + 0.044715f * v * v);
  const float tt = fast_exp2(2.3022078f * u);
  return v - v / (tt + 1.f);
}

// async global->LDS, 16B per lane; LDS dest is wave-uniform base + lane*16
__device__ __forceinline__ void gload_lds16(const bf16_t* g, bf16_t* l) {
  __builtin_amdgcn_global_load_lds(
      (const __attribute__((address_space(1))) void*)g,
      (__attribute__((address_space(3))) void*)l, 16, 0, 0);
}

// ---------------------------------------------------------------------------
// Transpose + fp32 -> bf16 convert:  in[K][N] fp32  ->  out[N][K] bf16
// ---------------------------------------------------------------------------
__global__ __launch_bounds__(256) void sa_transpose(const float* __restrict__ in,
                                                    bf16_t* __restrict__ out,
                                                    int K, int N) {
  __shared__ bf16_t tile[64][65];
  const int n0 = blockIdx.x * 64, k0 = blockIdx.y * 64;
  const int t = threadIdx.x;
#pragma unroll
  for (int i = 0; i < 16; ++i) {
    int idx = t + i * 256;
    int r = idx >> 6, c = idx & 63;
    tile[r][c] = (bf16_t)in[(size_t)(k0 + r) * N + n0 + c];
  }
  __syncthreads();
#pragma unroll
  for (int i = 0; i < 16; ++i) {
    int idx = t + i * 256;
    int r = idx >> 6, c = idx & 63;
    out[(size_t)(n0 + r) * K + k0 + c] = tile[c][r];
  }
}

// ---------------------------------------------------------------------------
// LayerNorm over D=1024 (fp32 input), one block per row. bf16 out (+opt fp32).
// ---------------------------------------------------------------------------
__global__ __launch_bounds__(256) void sa_layernorm(const float* __restrict__ in,
                                                    const float* __restrict__ gamma,
                                                    const float* __restrict__ beta,
                                                    bf16_t* __restrict__ out_bf,
                                                    float* __restrict__ out_f) {
  const int row = blockIdx.x, t = threadIdx.x;
  const float4 v = *(const float4*)(in + (size_t)row * 1024 + t * 4);
  float s  = v.x + v.y + v.z + v.w;
  float ss = v.x * v.x + v.y * v.y + v.z * v.z + v.w * v.w;
#pragma unroll
  for (int m = 1; m < 64; m <<= 1) {
    s  += __shfl_xor(s, m, 64);
    ss += __shfl_xor(ss, m, 64);
  }
  __shared__ float red[8];
  const int w = t >> 6, lane = t & 63;
  if (lane == 0) { red[w] = s; red[4 + w] = ss; }
  __syncthreads();
  s  = red[0] + red[1] + red[2] + red[3];
  ss = red[4] + red[5] + red[6] + red[7];
  const float mu   = s * (1.f / 1024.f);
  const float rstd = rsqrtf(ss * (1.f / 1024.f) - mu * mu + 1e-5f);
  const float4 gv = *(const float4*)(gamma + t * 4);
  const float4 bv = *(const float4*)(beta + t * 4);
  const float y0 = (v.x - mu) * rstd * gv.x + bv.x;
  const float y1 = (v.y - mu) * rstd * gv.y + bv.y;
  const float y2 = (v.z - mu) * rstd * gv.z + bv.z;
  const float y3 = (v.w - mu) * rstd * gv.w + bv.w;
  bf16x4 ob = { (bf16_t)y0, (bf16_t)y1, (bf16_t)y2, (bf16_t)y3 };
  *(bf16x4*)(out_bf + (size_t)row * 1024 + t * 4) = ob;
  if (out_f) {
    float4 of = { y0, y1, y2, y3 };
    *(float4*)(out_f + (size_t)row * 1024 + t * 4) = of;
  }
}

// ---------------------------------------------------------------------------
// LayerNorm over D=1024 (bf16 input), one block per row. bf16 out.
// ---------------------------------------------------------------------------
__global__ __launch_bounds__(256) void sa_layernorm_b(const bf16_t* __restrict__ in,
                                                      const float* __restrict__ gamma,
                                                      const float* __restrict__ beta,
                                                      bf16_t* __restrict__ out_bf) {
  const int row = blockIdx.x, t = threadIdx.x;
  const bf16x4 iv = *(const bf16x4*)(in + (size_t)row * 1024 + t * 4);
  const float v0 = (float)iv[0], v1 = (float)iv[1], v2 = (float)iv[2], v3 = (float)iv[3];
  float s  = v0 + v1 + v2 + v3;
  float ss = v0 * v0 + v1 * v1 + v2 * v2 + v3 * v3;
#pragma unroll
  for (int m = 1; m < 64; m <<= 1) {
    s  += __shfl_xor(s, m, 64);
    ss += __shfl_xor(ss, m, 64);
  }
  __shared__ float red[8];
  const int w = t >> 6, lane = t & 63;
  if (lane == 0) { red[w] = s; red[4 + w] = ss; }
  __syncthreads();
  s  = red[0] + red[1] + red[2] + red[3];
  ss = red[4] + red[5] + red[6] + red[7];
  const float mu   = s * (1.f / 1024.f);
  const float rstd = rsqrtf(ss * (1.f / 1024.f) - mu * mu + 1e-5f);
  const float4 gv = *(const float4*)(gamma + t * 4);
  const float4 bv = *(const float4*)(beta + t * 4);
  bf16x4 ob = { (bf16_t)((v0 - mu) * rstd * gv.x + bv.x),
                (bf16_t)((v1 - mu) * rstd * gv.y + bv.y),
                (bf16_t)((v2 - mu) * rstd * gv.z + bv.z),
                (bf16_t)((v3 - mu) * rstd * gv.w + bv.w) };
  *(bf16x4*)(out_bf + (size_t)row * 1024 + t * 4) = ob;
}

// ---------------------------------------------------------------------------
// GEMM v4 — "minimum 2-phase" schedule (T3 recipe): per K-tile
//   STAGE(next tile -> other buffer)   [issued FIRST: latency hides under MFMA]
//   ds_read frags (swizzled, zero-conflict)  ->  32 MFMA
//   __syncthreads() [built-in vmcnt drain: ~full-tile latency has passed]
// 128x128 tile, BK=64, 4 waves (2x2), dbuf-2 = 64KB LDS -> 2 blocks/CU (TLP).
// EPI: 0 = QKV split (Q scaled by 0.125*log2e; V transposed [bh][d][L]),
//      1 = bf16 store, 2 = fast-GELU->bf16, 3 = fp32 store + bf16 residual.
// ---------------------------------------------------------------------------
template <int EPI>
__global__ __launch_bounds__(256, 2) void sa_gemm4(const bf16_t* __restrict__ A,
                                                   const bf16_t* __restrict__ Bt,
                                                   const float* __restrict__ bias,
                                                   int K, int N,
                                                   float* __restrict__ fout,
                                                   bf16_t* __restrict__ bfout,
                                                   const bf16_t* __restrict__ res,
                                                   bf16_t* __restrict__ qb,
                                                   bf16_t* __restrict__ kb,
                                                   bf16_t* __restrict__ vb) {
  __shared__ __attribute__((aligned(16))) bf16_t As[2][128][64];  // 32 KB
  __shared__ __attribute__((aligned(16))) bf16_t Bs[2][128][64];  // 32 KB

  // bijective XCD swizzle (all grids are multiples of 8 blocks)
  const int nwg = gridDim.x * gridDim.y;
  const int flat = blockIdx.y * gridDim.x + blockIdx.x;
  const int wg = (flat & 7) * (nwg >> 3) + (flat >> 3);
  const int bx = wg % gridDim.x, by = wg / gridDim.x;

  const int m0 = by * 128, n0 = bx * 128;
  const int t = threadIdx.x;
  const int w = t >> 6, lane = t & 63;
  const int wr = w >> 1, wc = w & 1;
  const int fr = lane & 15, fq = lane >> 4;
  const int swz = fr & 7;
  const int srow = lane >> 3;                  // 0..7 within an 8-row chunk
  const int scol = ((lane & 7) ^ srow) * 8;    // pre-swizzled source col (elems)
  const int NT = K >> 6;

  const f32x4 fzero = { 0.f, 0.f, 0.f, 0.f };
  f32x4 acc[4][4];
#pragma unroll
  for (int mi = 0; mi < 4; ++mi)
#pragma unroll
    for (int ni = 0; ni < 4; ++ni) acc[mi][ni] = fzero;

  // stage K-tile tt into buffer sb: per wave 4 A-issues + 4 B-issues (1KB each)
  auto stage = [&](int tt, int sb) {
#pragma unroll
    for (int i = 0; i < 4; ++i) {
      const int c = w * 4 + i;                 // chunk 0..15 (8 rows each)
      const int row = c * 8 + srow;
      gload_lds16(A  + (size_t)(m0 + row) * K + tt * 64 + scol, &As[sb][c * 8][0]);
      gload_lds16(Bt + (size_t)(n0 + row) * K + tt * 64 + scol, &Bs[sb][c * 8][0]);
    }
  };

  stage(0, 0);
  __syncthreads();                             // tile 0 resident

  for (int tt = 0; tt < NT; ++tt) {
    const int cur = tt & 1;
    if (tt + 1 < NT) stage(tt + 1, cur ^ 1);   // issue early; hides under MFMA

    bf16x8 af[4][2], bfr[4][2];
#pragma unroll
    for (int mi = 0; mi < 4; ++mi)
#pragma unroll
      for (int kk = 0; kk < 2; ++kk)
        af[mi][kk] = *(const bf16x8*)&As[cur][wr * 64 + mi * 16 + fr][((kk * 4 + fq) ^ swz) * 8];
#pragma unroll
    for (int ni = 0; ni < 4; ++ni)
#pragma unroll
      for (int kk = 0; kk < 2; ++kk)
        bfr[ni][kk] = *(const bf16x8*)&Bs[cur][wc * 64 + ni * 16 + fr][((kk * 4 + fq) ^ swz) * 8];

    __builtin_amdgcn_s_setprio(1);
#pragma unroll
    for (int kk = 0; kk < 2; ++kk)
#pragma unroll
      for (int mi = 0; mi < 4; ++mi)
#pragma unroll
        for (int ni = 0; ni < 4; ++ni)
          acc[mi][ni] = MFMA_BF16(af[mi][kk], bfr[ni][kk], acc[mi][ni]);
    __builtin_amdgcn_s_setprio(0);

    __syncthreads();                           // drains vmcnt: next tile ready
  }

#pragma unroll
  for (int ni = 0; ni < 4; ++ni) {
    const int n = n0 + wc * 64 + ni * 16 + fr;
    const float bn = bias[n];
#pragma unroll
    for (int mi = 0; mi < 4; ++mi) {
      const int mbase = m0 + wr * 64 + mi * 16 + fq * 4;
      float vv[4];
#pragma unroll
      for (int r = 0; r < 4; ++r) vv[r] = acc[mi][ni][r] + bn;
      if constexpr (EPI == 0) {
        const int which = n >> 10;
        const int hh = (n >> 6) & 15;
        const int d = n & 63;
        const int b = mbase >> 11, l = mbase & 2047;
        if (which == 0) {
#pragma unroll
          for (int r = 0; r < 4; ++r)
            qb[((size_t)(b * 16 + hh) * 2048 + l + r) * 64 + d] =
                (bf16_t)(vv[r] * (0.125f * 1.44269504088896340736f));
        } else if (which == 1) {
#pragma unroll
          for (int r = 0; r < 4; ++r)
            kb[((size_t)(b * 16 + hh) * 2048 + l + r) * 64 + d] = (bf16_t)vv[r];
        } else {
          bf16x4 pv = { (bf16_t)vv[0], (bf16_t)vv[1], (bf16_t)vv[2], (bf16_t)vv[3] };
          *(bf16x4*)(vb + ((size_t)(b * 16 + hh) * 64 + d) * 2048 + l) = pv;
        }
      } else if constexpr (EPI == 1) {
#pragma unroll
        for (int r = 0; r < 4; ++r)
          bfout[(size_t)(mbase + r) * N + n] = (bf16_t)vv[r];
      } else if constexpr (EPI == 2) {
#pragma unroll
        for (int r = 0; r < 4; ++r)
          bfout[(size_t)(mbase + r) * N + n] = (bf16_t)fast_gelu(vv[r]);
      } else {
#pragma unroll
        for (int r = 0; r < 4; ++r)
          fout[(size_t)(mbase + r) * N + n] = vv[r] + (float)res[(size_t)(mbase + r) * N + n];
      }
    }
  }
}

// ---------------------------------------------------------------------------
// Flash attention (unchanged from r8): swapped-QK^T + fixed-reference softmax,
// zero-conflict XOR-swizzled LDS, XCD-swizzled grid.
// ---------------------------------------------------------------------------
__global__ __launch_bounds__(256) void sa_attn(const bf16_t* __restrict__ qb,
                                               const bf16_t* __restrict__ kb,
                                               const bf16_t* __restrict__ vb,
                                               bf16_t* __restrict__ out) {
  __shared__ __attribute__((aligned(16))) bf16_t Ks[64][64];      // also Q staging
  __shared__ __attribute__((aligned(16))) bf16_t Vt[64][64];      // Vt[d][kv]
  __shared__ __attribute__((aligned(16))) bf16_t Ps[4][16][64];   // P[q][kv] per wave

  const int nwg = gridDim.x * gridDim.y;            // 2048
  const int flat = blockIdx.y * gridDim.x + blockIdx.x;
  const int wg = (flat & 7) * (nwg >> 3) + (flat >> 3);
  const int qblk = wg & 31, bh = wg >> 5;

  const int t = threadIdx.x, w = t >> 6, lane = t & 63;
  const int fr = lane & 15, fq = lane >> 4;
  const int fx = fr & 7;
  const size_t base = (size_t)bh * 2048 * 64;
  const f32x4 fzero = { 0.f, 0.f, 0.f, 0.f };

  const int row0 = t >> 3;
  const int u0 = t & 7;
  const int sc = (u0 ^ (row0 & 7)) * 8;
  const int gc = u0 * 8;

  *(bf16x8*)&Ks[row0][sc] =
      *(const bf16x8*)(qb + base + (size_t)(qblk * 64 + row0) * 64 + gc);
  *(bf16x8*)&Ks[row0 + 32][sc] =
      *(const bf16x8*)(qb + base + (size_t)(qblk * 64 + row0 + 32) * 64 + gc);

  bf16x8 kreg0, kreg1, vreg0, vreg1;
  kreg0 = *(const bf16x8*)(kb + base + (size_t)row0 * 64 + gc);
  kreg1 = *(const bf16x8*)(kb + base + (size_t)(row0 + 32) * 64 + gc);
  vreg0 = *(const bf16x8*)(vb + base + (size_t)row0 * 2048 + gc);
  vreg1 = *(const bf16x8*)(vb + base + (size_t)(row0 + 32) * 2048 + gc);

  __syncthreads();
  bf16x8 qf[2];
  qf[0] = *(const bf16x8*)&Ks[w * 16 + fr][((0 * 4 + fq) ^ fx) * 8];
  qf[1] = *(const bf16x8*)&Ks[w * 16 + fr][((1 * 4 + fq) ^ fx) * 8];

  f32x4 o_acc[4];
#pragma unroll
  for (int dt = 0; dt < 4; ++dt) o_acc[dt] = fzero;
  f32x4 l4 = fzero;

  for (int kv0 = 0; kv0 < 2048; kv0 += 64) {
    __syncthreads();
    *(bf16x8*)&Ks[row0][sc] = kreg0;
    *(bf16x8*)&Ks[row0 + 32][sc] = kreg1;
    *(bf16x8*)&Vt[row0][sc] = vreg0;
    *(bf16x8*)&Vt[row0 + 32][sc] = vreg1;
    if (kv0 + 64 < 2048) {
      const int kvn = kv0 + 64;
      kreg0 = *(const bf16x8*)(kb + base + (size_t)(kvn + row0) * 64 + gc);
      kreg1 = *(const bf16x8*)(kb + base + (size_t)(kvn + row0 + 32) * 64 + gc);
      vreg0 = *(const bf16x8*)(vb + base + (size_t)row0 * 2048 + kvn + gc);
      vreg1 = *(const bf16x8*)(vb + base + (size_t)(row0 + 32) * 2048 + kvn + gc);
    }
    __syncthreads();

    f32x4 s[4];
#pragma unroll
    for (int kvt = 0; kvt < 4; ++kvt) s[kvt] = fzero;
    __builtin_amdgcn_s_setprio(1);
#pragma unroll
    for (int kk = 0; kk < 2; ++kk) {
#pragma unroll
      for (int kvt = 0; kvt < 4; ++kvt) {
        bf16x8 kf = *(const bf16x8*)&Ks[kvt * 16 + fr][((kk * 4 + fq) ^ fx) * 8];
        s[kvt] = MFMA_BF16(kf, qf[kk], s[kvt]);
      }
    }
    __builtin_amdgcn_s_setprio(0);

#pragma unroll
    for (int kvt = 0; kvt < 4; ++kvt) {
#pragma unroll
      for (int r = 0; r < 4; ++r) s[kvt][r] = fast_exp2(s[kvt][r]);
      l4 += s[kvt];
      bf16x4 pr = { (bf16_t)s[kvt][0], (bf16_t)s[kvt][1],
                    (bf16_t)s[kvt][2], (bf16_t)s[kvt][3] };
      *(bf16x4*)&Ps[w][fr][(((kvt * 2 + (fq >> 1)) ^ fx) * 8) + (fq & 1) * 4] = pr;
    }

    __builtin_amdgcn_s_setprio(1);
#pragma unroll
    for (int ks = 0; ks < 2; ++ks) {
      bf16x8 pf = *(const bf16x8*)&Ps[w][fr][((ks * 4 + fq) ^ fx) * 8];
#pragma unroll
      for (int dt = 0; dt < 4; ++dt) {
        bf16x8 vf = *(const bf16x8*)&Vt[dt * 16 + fr][((ks * 4 + fq) ^ fx) * 8];
        o_acc[dt] = MFMA_BF16(vf, pf, o_acc[dt]);
      }
    }
    __builtin_amdgcn_s_setprio(0);
  }

  float l_run = l4[0] + l4[1] + l4[2] + l4[3];
  l_run += __shfl_xor(l_run, 16, 64);
  l_run += __shfl_xor(l_run, 32, 64);
  const float linv = 1.f / l_run;
  const int b = bh >> 4, h = bh & 15;
  const int qg = qblk * 64 + w * 16 + fr;
#pragma unroll
  for (int dt = 0; dt < 4; ++dt) {
    bf16x4 ov;
#pragma unroll
    for (int r = 0; r < 4; ++r) ov[r] = (bf16_t)(o_acc[dt][r] * linv);
    const int d = dt * 16 + fq * 4;
    *(bf16x4*)(out + ((size_t)(b * 2048 + qg)) * 1024 + h * 64 + d) = ov;
  }
}

// ---------------------------------------------------------------------------
extern "C" void kernel_launch(void* const* d_in, const int* in_sizes, int n_in,
                              void* d_out, int out_size, void* d_ws, size_t ws_size,
                              hipStream_t stream) {
  const float* x      = (const float*)d_in[0];
  const float* qkv_w  = (const float*)d_in[1];
  const float* qkv_b  = (const float*)d_in[2];
  const float* out_w  = (const float*)d_in[3];
  const float* out_b  = (const float*)d_in[4];
  const float* ln1_g  = (const float*)d_in[5];
  const float* ln1_b  = (const float*)d_in[6];
  const float* ln2_g  = (const float*)d_in[7];
  const float* ln2_b  = (const float*)d_in[8];
  const float* ffn_w1 = (const float*)d_in[9];
  const float* ffn_b1 = (const float*)d_in[10];
  const float* ffn_w2 = (const float*)d_in[11];
  const float* ffn_b2 = (const float*)d_in[12];
  float* outp = (float*)d_out;

  char* p = (char*)d_ws;
  auto alloc = [&](size_t bytes) { char* r = p; p += bytes; return r; };
  bf16_t* qkvw_t = (bf16_t*)alloc((size_t)3072 * 1024 * 2);
  bf16_t* outw_t = (bf16_t*)alloc((size_t)1024 * 1024 * 2);
  bf16_t* w1_t   = (bf16_t*)alloc((size_t)4096 * 1024 * 2);
  bf16_t* w2_t   = (bf16_t*)alloc((size_t)1024 * 4096 * 2);
  bf16_t* h_bf   = (bf16_t*)alloc((size_t)8192 * 1024 * 2);
  bf16_t* q_buf  = (bf16_t*)alloc((size_t)8192 * 1024 * 2);
  bf16_t* k_buf  = (bf16_t*)alloc((size_t)8192 * 1024 * 2);
  bf16_t* v_buf  = (bf16_t*)alloc((size_t)8192 * 1024 * 2);
  bf16_t* a_bf   = (bf16_t*)alloc((size_t)8192 * 1024 * 2);
  bf16_t* o_bf   = (bf16_t*)alloc((size_t)8192 * 1024 * 2);
  bf16_t* out_bf = (bf16_t*)alloc((size_t)8192 * 1024 * 2);
  bf16_t* t_bf   = (bf16_t*)alloc((size_t)8192 * 4096 * 2);

  sa_transpose<<<dim3(3072 / 64, 1024 / 64), 256, 0, stream>>>(qkv_w, qkvw_t, 1024, 3072);
  sa_transpose<<<dim3(1024 / 64, 1024 / 64), 256, 0, stream>>>(out_w, outw_t, 1024, 1024);
  sa_transpose<<<dim3(4096 / 64, 1024 / 64), 256, 0, stream>>>(ffn_w1, w1_t, 1024, 4096);
  sa_transpose<<<dim3(1024 / 64, 4096 / 64), 256, 0, stream>>>(ffn_w2, w2_t, 4096, 1024);

  sa_layernorm<<<8192, 256, 0, stream>>>(x, ln1_g, ln1_b, h_bf, nullptr);

  sa_gemm4<0><<<dim3(3072 / 128, 8192 / 128), 256, 0, stream>>>(
      h_bf, qkvw_t, qkv_b, 1024, 3072, nullptr, nullptr, nullptr, q_buf, k_buf, v_buf);

  sa_attn<<<dim3(32, 64), 256, 0, stream>>>(q_buf, k_buf, v_buf, a_bf);

  sa_gemm4<1><<<dim3(1024 / 128, 8192 / 128), 256, 0, stream>>>(
      a_bf, outw_t, out_b, 1024, 1024, nullptr, o_bf, nullptr, nullptr, nullptr, nullptr);

  sa_layernorm_b<<<8192, 256, 0, stream>>>(o_bf, ln2_g, ln2_b, out_bf);

  sa_gemm4<2><<<dim3(4096 / 128, 8192 / 128), 256, 0, stream>>>(
      out_bf, w1_t, ffn_b1, 1024, 4096, nullptr, t_bf, nullptr, nullptr, nullptr, nullptr);

  sa_gemm4<3><<<dim3(1024 / 128, 8192 / 128), 256, 0, stream>>>(
      t_bf, w2_t, ffn_b2, 4096, 1024, outp, nullptr, out_bf, nullptr, nullptr, nullptr);
}